// Round 6
// baseline (167.975 us; speedup 1.0000x reference)
//
#include <hip/hip_runtime.h>
#include <hip/hip_bf16.h>

typedef unsigned short u16;
typedef unsigned int u32;

#define NEG_SLOPE 0.2f
#define ZTOLF 1e-9f
#define CAP 256          // max tracked nonzeros per column/row of S (mean ~102, sigma ~10)

__device__ __forceinline__ float b2f(u16 v) {
  return __uint_as_float(((u32)v) << 16);
}
__device__ __forceinline__ u16 f2b(float f) {
  u32 u = __float_as_uint(f);
  return (u16)((u + 0x7fffu + ((u >> 16) & 1u)) >> 16);  // RNE
}
__device__ __forceinline__ float ldin(const void* p, size_t i, int isbf) {
  return isbf ? b2f(((const u16*)p)[i]) : ((const float*)p)[i];
}

// ---------------- K0: detect input dtype + zero the (padded) counters ----------------
__global__ __launch_bounds__(256) void k_detect(const u32* __restrict__ xw,
                                                u32* __restrict__ flag,
                                                uint4* __restrict__ cnt_p4,   // 2048*16 u32 = 8192 uint4
                                                uint4* __restrict__ rcnt4) {  // 2048 u32 = 512 uint4
  __shared__ u32 cnt_s[4];
  const int tid = threadIdx.x;
  const uint4 z = make_uint4(0u, 0u, 0u, 0u);
  for (int i = tid; i < 8192; i += 256) cnt_p4[i] = z;
  for (int i = tid; i < 512; i += 256) rcnt4[i] = z;
  const u32 w = xw[tid];
  const u32 e = (w >> 7) & 0xffu;
  const int in = (e >= 118u && e <= 131u) ? 1 : 0;
  unsigned long long bal = __ballot(in);
  const int lane = tid & 63, wid = tid >> 6;
  if (lane == 0) cnt_s[wid] = (u32)__popcll(bal);
  __syncthreads();
  if (tid == 0) {
    u32 tot = cnt_s[0] + cnt_s[1] + cnt_s[2] + cnt_s[3];
    flag[0] = (tot >= 128u) ? 1u : 0u;
  }
}

// ---------------- K1: Wx[bp][n][f] (bf16) + fused s1t/s2t epilogue ----------------
__global__ __launch_bounds__(256) void k_wx(const void* __restrict__ x,
                                            const void* __restrict__ W,
                                            const void* __restrict__ a,
                                            u16* __restrict__ Wx,
                                            float* __restrict__ s1t,
                                            float* __restrict__ s2t,
                                            const u32* __restrict__ flag) {
  __shared__ float Wt[64 * 68];  // [g][f]; aliased as red1/red2 in epilogue
  __shared__ float Xs[64 * 64];  // [g][n]
  const int isbf = (int)flag[0];
  const int tid = threadIdx.x;
  const int n0 = blockIdx.x * 64;
  const int bp = blockIdx.y;
  const int b = bp >> 2, p = bp & 3;
  const int tn = tid & 15, tf = tid >> 4;
  float acc[4][4] = {{0.f}};
  const size_t Wbase = (size_t)p * 64 * 128;
  const size_t xbase = (size_t)b * 128 * 2048;
  for (int kt = 0; kt < 2; ++kt) {
    const int g0 = kt * 64;
#pragma unroll
    for (int j = 0; j < 16; ++j) {
      int idx = tid + j * 256;
      int f = idx >> 6, g = idx & 63;
      Wt[g * 68 + f] = ldin(W, Wbase + (size_t)f * 128 + g0 + g, isbf);
    }
#pragma unroll
    for (int j = 0; j < 16; ++j) {
      int idx = tid + j * 256;
      int g = idx >> 6, nn = idx & 63;
      Xs[g * 64 + nn] = ldin(x, xbase + (size_t)(g0 + g) * 2048 + n0 + nn, isbf);
    }
    __syncthreads();
#pragma unroll 4
    for (int g = 0; g < 64; ++g) {
      float4 wv = *(const float4*)&Wt[g * 68 + tf * 4];
      float4 xv = *(const float4*)&Xs[g * 64 + tn * 4];
      acc[0][0] += wv.x * xv.x; acc[0][1] += wv.x * xv.y; acc[0][2] += wv.x * xv.z; acc[0][3] += wv.x * xv.w;
      acc[1][0] += wv.y * xv.x; acc[1][1] += wv.y * xv.y; acc[1][2] += wv.y * xv.z; acc[1][3] += wv.y * xv.w;
      acc[2][0] += wv.z * xv.x; acc[2][1] += wv.z * xv.y; acc[2][2] += wv.z * xv.z; acc[2][3] += wv.z * xv.w;
      acc[3][0] += wv.w * xv.x; acc[3][1] += wv.w * xv.y; acc[3][2] += wv.w * xv.z; acc[3][3] += wv.w * xv.w;
    }
    __syncthreads();
  }
#pragma unroll
  for (int j = 0; j < 4; ++j) {
    int n = n0 + tn * 4 + j;
    u32 lo = (u32)f2b(acc[0][j]) | ((u32)f2b(acc[1][j]) << 16);
    u32 hi = (u32)f2b(acc[2][j]) | ((u32)f2b(acc[3][j]) << 16);
    *(uint2*)(Wx + ((size_t)(bp * 2048 + n) * 64 + tf * 4)) = make_uint2(lo, hi);
  }
  float a1v[4], a2v[4];
#pragma unroll
  for (int fi = 0; fi < 4; ++fi) {
    a1v[fi] = ldin(a, (size_t)p * 128 + tf * 4 + fi, isbf);
    a2v[fi] = ldin(a, (size_t)p * 128 + 64 + tf * 4 + fi, isbf);
  }
  float* red1 = Wt;             // 64*17 floats
  float* red2 = Wt + 64 * 17;   // 64*17 floats
#pragma unroll
  for (int j = 0; j < 4; ++j) {
    float p1 = a1v[0] * acc[0][j] + a1v[1] * acc[1][j] + a1v[2] * acc[2][j] + a1v[3] * acc[3][j];
    float p2 = a2v[0] * acc[0][j] + a2v[1] * acc[1][j] + a2v[2] * acc[2][j] + a2v[3] * acc[3][j];
    red1[(tn * 4 + j) * 17 + tf] = p1;
    red2[(tn * 4 + j) * 17 + tf] = p2;
  }
  __syncthreads();
  if (tid < 64) {
    float v1 = 0.f, v2 = 0.f;
#pragma unroll
    for (int k = 0; k < 16; ++k) {
      v1 += red1[tid * 17 + k];
      v2 += red2[tid * 17 + k];
    }
    s1t[(size_t)(n0 + tid) * 16 + bp] = v1;
    s2t[(size_t)(n0 + tid) * 16 + bp] = v2;
  }
}

// ---------------- K2: block per row. Row lists (packed n|slot|has_slot + sv) via prefix scan;
// column lists via line-padded atomics. ----------------
__global__ __launch_bounds__(256) void k_csc(const void* __restrict__ S,
                                             u32* __restrict__ cnt_p,
                                             u32* __restrict__ col_m,
                                             float* __restrict__ col_v,
                                             u32* __restrict__ rcnt,
                                             u32* __restrict__ row_e,
                                             float* __restrict__ row_v,
                                             const u32* __restrict__ flag) {
  __shared__ u32 wsum[4];
  const int isbf = (int)flag[0];
  const int m = blockIdx.x;
  const int tid = threadIdx.x;
  const int lane = tid & 63, wid = tid >> 6;
  const int n0 = tid * 8;
  float v[8];
  if (isbf) {
    uint4 pk = ((const uint4*)S)[(size_t)m * 256 + tid];
    u32 wv[4] = {pk.x, pk.y, pk.z, pk.w};
#pragma unroll
    for (int j = 0; j < 4; ++j) {
      v[2 * j]     = b2f((u16)(wv[j] & 0xffffu));
      v[2 * j + 1] = b2f((u16)(wv[j] >> 16));
    }
  } else {
    float4 f0 = ((const float4*)S)[(size_t)m * 512 + 2 * tid];
    float4 f1 = ((const float4*)S)[(size_t)m * 512 + 2 * tid + 1];
    v[0] = f0.x; v[1] = f0.y; v[2] = f0.z; v[3] = f0.w;
    v[4] = f1.x; v[5] = f1.y; v[6] = f1.z; v[7] = f1.w;
  }
  u32 rflags = 0, rc = 0;
#pragma unroll
  for (int j = 0; j < 8; ++j) {
    const int n = n0 + j;
    const float svd = (n == m) ? v[j] + 1.f : v[j];
    if (fabsf(svd) > ZTOLF) { rflags |= 1u << j; rc++; }
  }
  u32 inc = rc;
#pragma unroll
  for (int off = 1; off < 64; off <<= 1) {
    u32 y = __shfl_up(inc, off);
    if (lane >= off) inc += y;
  }
  if (lane == 63) wsum[wid] = inc;
  __syncthreads();
  u32 wbase = 0;
#pragma unroll
  for (int k = 0; k < 4; ++k) wbase += (k < wid) ? wsum[k] : 0u;
  u32 pos = wbase + inc - rc;
#pragma unroll
  for (int j = 0; j < 8; ++j) {
    const int n = n0 + j;
    const float sv = v[j];
    u32 slot = 0xffffffffu;
    if (sv != 0.f) {
      u32 s = atomicAdd(&cnt_p[(size_t)n * 16], 1u);
      if (s < CAP) {
        col_m[(size_t)n * CAP + s] = (u32)m;
        col_v[(size_t)n * CAP + s] = sv;
        slot = s;
      }
    }
    if ((rflags >> j) & 1u) {
      if (pos < CAP) {
        const u32 hs = (slot != 0xffffffffu) ? 1u : 0u;
        row_e[(size_t)m * CAP + pos] = (u32)n | ((slot & 0xffu) << 11) | (hs << 19);
        row_v[(size_t)m * CAP + pos] = sv;
      }
      pos++;
    }
  }
  if (tid == 255) rcnt[m] = min(wbase + inc, (u32)CAP);
}

// ---------------- K3: sparse softmax stats (wave per row) + weight scatter to col_w ----------------
__global__ __launch_bounds__(256) void k_rows(const u32* __restrict__ rcnt,
                                              const u32* __restrict__ row_e,
                                              const float* __restrict__ row_v,
                                              const float* __restrict__ s1t,
                                              const float* __restrict__ s2t,
                                              float* __restrict__ col_w) {
  __shared__ float4 stat_s[4][16];   // per-wave (s2, rowmax, invsum, 0)
  const int tid = threadIdx.x;
  const int lane = tid & 63, wv = tid >> 6;
  const int m = blockIdx.x * 4 + wv;      // one wave per row
  const int c2 = min((int)rcnt[m], CAP);
  u32 pk[4];
#pragma unroll
  for (int I = 0; I < 4; ++I) {
    int i = lane + I * 64;
    pk[I] = (i < c2) ? row_e[(size_t)m * CAP + i] : 0xffffffffu;
  }
  const float s2v = (lane < 16) ? s2t[(size_t)m * 16 + lane] : 0.f;
  float my_rmx = 0.f, my_inv = 0.f;
#pragma unroll
  for (int g = 0; g < 4; ++g) {           // bp groups of 4
    float4 sg[4];
#pragma unroll
    for (int I = 0; I < 4; ++I)
      sg[I] = (pk[I] != 0xffffffffu)
                ? *(const float4*)&s1t[(size_t)(pk[I] & 0x7ffu) * 16 + g * 4]
                : make_float4(-3e38f, -3e38f, -3e38f, -3e38f);
#pragma unroll
    for (int q = 0; q < 4; ++q) {
      const int bp = g * 4 + q;
      const float s2m = __shfl(s2v, bp);
      float s1max = -3e38f;
#pragma unroll
      for (int I = 0; I < 4; ++I) {
        float xv = (q == 0) ? sg[I].x : (q == 1) ? sg[I].y : (q == 2) ? sg[I].z : sg[I].w;
        s1max = fmaxf(s1max, xv);
      }
#pragma unroll
      for (int off = 32; off; off >>= 1) s1max = fmaxf(s1max, __shfl_xor(s1max, off));
      float rmx = s2m + s1max;
      rmx = rmx >= 0.f ? rmx : NEG_SLOPE * rmx;
      float sm = 0.f;
#pragma unroll
      for (int I = 0; I < 4; ++I) {
        float xv = (q == 0) ? sg[I].x : (q == 1) ? sg[I].y : (q == 2) ? sg[I].z : sg[I].w;
        float e = xv + s2m;
        e = e >= 0.f ? e : NEG_SLOPE * e;
        sm += __expf(e - rmx);
      }
#pragma unroll
      for (int off = 32; off; off >>= 1) sm += __shfl_xor(sm, off);
      const bool any = (s1max > -1e38f);
      const float rmxo = any ? rmx : 0.f;
      const float inv = any ? 1.f / sm : 0.f;
      if (lane == bp) { my_rmx = rmxo; my_inv = inv; }
    }
  }
  if (lane < 16) stat_s[wv][lane] = make_float4(s2v, my_rmx, my_inv, 0.f);
  // phase 2: weight scatter (same-wave LDS read; program order guarantees visibility)
#pragma unroll
  for (int I = 0; I < 4; ++I) {
    const u32 p = pk[I];
    if (p == 0xffffffffu) continue;
    if (!((p >> 19) & 1u)) continue;      // no column slot (pure-diagonal sv==0)
    const int n = (int)(p & 0x7ffu);
    const int slot = (int)((p >> 11) & 0xffu);
    const float sv = row_v[(size_t)m * CAP + lane + I * 64];
    float* dst = col_w + ((size_t)n * CAP + slot) * 16;
#pragma unroll
    for (int g = 0; g < 4; ++g) {
      const float4 s1v = *(const float4*)&s1t[(size_t)n * 16 + g * 4];
      float4 wo;
#pragma unroll
      for (int q = 0; q < 4; ++q) {
        const float4 st = stat_s[wv][g * 4 + q];
        float xv = (q == 0) ? s1v.x : (q == 1) ? s1v.y : (q == 2) ? s1v.z : s1v.w;
        float e = xv + st.x;
        e = e >= 0.f ? e : NEG_SLOPE * e;
        const float w = sv * __expf(e - st.y) * st.z;
        if (q == 0) wo.x = w; else if (q == 1) wo.y = w; else if (q == 2) wo.z = w; else wo.w = w;
      }
      *(float4*)&dst[g * 4] = wo;
    }
  }
}

// ---------------- K4: y[bp][f][n] = relu( sum_m Wx[bp][m][f] * w[m][n][bp] ) ----------------
// 512 threads: 8 waves = 4 bp-groups x 2 entry-halves. Weights pre-computed (coalesced load).
__global__ __launch_bounds__(512, 8) void k_out(const u16* __restrict__ Wx,
                                                const u32* __restrict__ cnt_p,
                                                const u32* __restrict__ col_m,
                                                const float* __restrict__ col_v,
                                                const float* __restrict__ col_w,
                                                void* __restrict__ out,
                                                const u32* __restrict__ flag) {
  __shared__ u32 lds_mo[CAP];        // m*64 element offsets
  __shared__ float lds_w[CAP * 16];  // [i][bp], 16 KB
  __shared__ float lds_r[256 * 4];   // half-1 partials (4 KB)
  const int isbf = (int)flag[0];
  const int tid = threadIdx.x;
  const int bid = blockIdx.x;
  const int n = ((bid & 7) << 8) | (bid >> 3);   // XCD swizzle
  const int c = min((int)cnt_p[(size_t)n * 16], CAP);
  const int cpad = (c + 7) & ~7;                 // 2 halves x unroll-4
  u32 mreg = 0; float svreg = 0.f;
  if (tid < cpad) {
    mreg  = (tid < c) ? col_m[(size_t)n * CAP + tid] : 0u;
    svreg = (tid < c) ? col_v[(size_t)n * CAP + tid] : 0.f;
  }
  const float4* cw4 = (const float4*)(col_w + (size_t)n * CAP * 16);
  const int w4 = cpad * 4;
  for (int k = tid; k < w4; k += 512)
    ((float4*)lds_w)[k] = (k < c * 4) ? cw4[k] : make_float4(0.f, 0.f, 0.f, 0.f);
  __syncthreads();
  if (tid < cpad) {
    if (tid < c && (int)mreg == n && fabsf(svreg + 1.f) <= ZTOLF) {
      // masked-out diagonal (|S+I| <= tol): weight is exactly 0, never written by k_rows
#pragma unroll
      for (int q = 0; q < 4; ++q) ((float4*)lds_w)[tid * 4 + q] = make_float4(0.f, 0.f, 0.f, 0.f);
    }
    lds_mo[tid] = mreg * 64u;        // element offset into Wx[bp]
  }
  __syncthreads();
  const int lane = tid & 63, wvi = tid >> 6;
  const int h = wvi >> 2;
  const int bp = (wvi & 3) * 4 + (lane >> 4);
  const int f4 = lane & 15;
  const u16* wxp = Wx + (size_t)bp * (2048 * 64) + f4 * 4;
  float ac0 = 0.f, ac1 = 0.f, ac2 = 0.f, ac3 = 0.f;
  for (int base = h * 4; base < cpad; base += 8) {
    uint2 wd[4]; float ww[4];
#pragma unroll
    for (int j = 0; j < 4; ++j) {
      const int i = base + j;
      const u32 off = lds_mo[i];
      wd[j] = *(const uint2*)(wxp + off);
      ww[j] = lds_w[i * 16 + bp];
    }
#pragma unroll
    for (int j = 0; j < 4; ++j) {
      const float w = ww[j];
      ac0 += w * b2f((u16)(wd[j].x & 0xffffu));
      ac1 += w * b2f((u16)(wd[j].x >> 16));
      ac2 += w * b2f((u16)(wd[j].y & 0xffffu));
      ac3 += w * b2f((u16)(wd[j].y >> 16));
    }
  }
  if (h == 1)
    *(float4*)&lds_r[(bp * 16 + f4) * 4] = make_float4(ac0, ac1, ac2, ac3);
  __syncthreads();
  if (h == 0) {
    float4 r = *(const float4*)&lds_r[(bp * 16 + f4) * 4];
    const float o0 = fmaxf(ac0 + r.x, 0.f), o1 = fmaxf(ac1 + r.y, 0.f);
    const float o2 = fmaxf(ac2 + r.z, 0.f), o3 = fmaxf(ac3 + r.w, 0.f);
    const size_t r0 = (size_t)(bp * 64 + f4 * 4);
    if (isbf) {
      u16* ob = (u16*)out;
      ob[(r0 + 0) * 2048 + n] = f2b(o0);
      ob[(r0 + 1) * 2048 + n] = f2b(o1);
      ob[(r0 + 2) * 2048 + n] = f2b(o2);
      ob[(r0 + 3) * 2048 + n] = f2b(o3);
    } else {
      float* of = (float*)out;
      of[(r0 + 0) * 2048 + n] = o0;
      of[(r0 + 1) * 2048 + n] = o1;
      of[(r0 + 2) * 2048 + n] = o2;
      of[(r0 + 3) * 2048 + n] = o3;
    }
  }
}

extern "C" void kernel_launch(void* const* d_in, const int* in_sizes, int n_in,
                              void* d_out, int out_size, void* d_ws, size_t ws_size,
                              hipStream_t stream) {
  // inputs (dtype auto-detected): x (4,128,2048), a (4,1,128), W (4,1,64,128), S (1,2048,2048)
  const void* x = d_in[0];
  const void* a = d_in[1];
  const void* W = d_in[2];
  const void* S = d_in[3];

  char* ws = (char*)d_ws;
  u16* Wx      = (u16*)ws;                               // 4 MiB
  float* s1t   = (float*)(ws + 4u * 1024 * 1024);        // 128 KiB
  float* s2t   = s1t + 2048 * 16;                        // 128 KiB
  u32* cnt_p   = (u32*)(s2t + 2048 * 16);                // 128 KiB (1 counter / 64B line)
  u32* rcnt    = cnt_p + 2048 * 16;                      // 8 KiB
  u32* col_m   = rcnt + 2048;                            // 2 MiB
  float* col_v = (float*)(col_m + 2048 * CAP);           // 2 MiB
  u32* row_e   = (u32*)(col_v + 2048 * CAP);             // 2 MiB
  float* row_v = (float*)(row_e + 2048 * CAP);           // 2 MiB
  float* col_w = row_v + 2048 * CAP;                     // 2048*CAP*16*4 = 32 MiB
  u32* flag    = (u32*)(col_w + (size_t)2048 * CAP * 16);// 4 B
  // total ~44.5 MiB

  k_detect<<<1, 256, 0, stream>>>((const u32*)x, flag, (uint4*)cnt_p, (uint4*)rcnt);
  k_wx<<<dim3(32, 16), 256, 0, stream>>>(x, W, a, Wx, s1t, s2t, flag);
  k_csc<<<2048, 256, 0, stream>>>(S, cnt_p, col_m, col_v, rcnt, row_e, row_v, flag);
  k_rows<<<512, 256, 0, stream>>>(rcnt, row_e, row_v, s1t, s2t, col_w);
  k_out<<<2048, 512, 0, stream>>>(Wx, cnt_p, col_m, col_v, col_w, d_out, flag);
}

// Round 7
// 166.047 us; speedup vs baseline: 1.0116x; 1.0116x over previous
//
#include <hip/hip_runtime.h>
#include <hip/hip_bf16.h>

typedef unsigned short u16;
typedef unsigned int u32;

#define NEG_SLOPE 0.2f
#define ZTOLF 1e-9f
#define CAP 256          // max tracked nonzeros per column/row of S (mean ~102, sigma ~10)

__device__ __forceinline__ float b2f(u16 v) {
  return __uint_as_float(((u32)v) << 16);
}
__device__ __forceinline__ u16 f2b(float f) {
  u32 u = __float_as_uint(f);
  return (u16)((u + 0x7fffu + ((u >> 16) & 1u)) >> 16);  // RNE
}
__device__ __forceinline__ float ldin(const void* p, size_t i, int isbf) {
  return isbf ? b2f(((const u16*)p)[i]) : ((const float*)p)[i];
}

// ---------------- K0: detect input dtype + zero the (padded) counters ----------------
__global__ __launch_bounds__(256) void k_detect(const u32* __restrict__ xw,
                                                u32* __restrict__ flag,
                                                uint4* __restrict__ cnt_p4,   // 2048*16 u32 = 8192 uint4
                                                uint4* __restrict__ rcnt4) {  // 2048 u32 = 512 uint4
  __shared__ u32 cnt_s[4];
  const int tid = threadIdx.x;
  const uint4 z = make_uint4(0u, 0u, 0u, 0u);
  for (int i = tid; i < 8192; i += 256) cnt_p4[i] = z;
  for (int i = tid; i < 512; i += 256) rcnt4[i] = z;
  const u32 w = xw[tid];
  const u32 e = (w >> 7) & 0xffu;
  const int in = (e >= 118u && e <= 131u) ? 1 : 0;
  unsigned long long bal = __ballot(in);
  const int lane = tid & 63, wid = tid >> 6;
  if (lane == 0) cnt_s[wid] = (u32)__popcll(bal);
  __syncthreads();
  if (tid == 0) {
    u32 tot = cnt_s[0] + cnt_s[1] + cnt_s[2] + cnt_s[3];
    flag[0] = (tot >= 128u) ? 1u : 0u;
  }
}

// ---------------- K1: Wx[m][bp][f] (bf16, node-major!) + fused s1t/s2t epilogue ----------------
__global__ __launch_bounds__(256) void k_wx(const void* __restrict__ x,
                                            const void* __restrict__ W,
                                            const void* __restrict__ a,
                                            u16* __restrict__ Wx,
                                            float* __restrict__ s1t,
                                            float* __restrict__ s2t,
                                            const u32* __restrict__ flag) {
  __shared__ float Wt[64 * 68];  // [g][f]; aliased as red1/red2 in epilogue
  __shared__ float Xs[64 * 64];  // [g][n]
  const int isbf = (int)flag[0];
  const int tid = threadIdx.x;
  const int n0 = blockIdx.x * 64;
  const int bp = blockIdx.y;
  const int b = bp >> 2, p = bp & 3;
  const int tn = tid & 15, tf = tid >> 4;
  float acc[4][4] = {{0.f}};
  const size_t Wbase = (size_t)p * 64 * 128;
  const size_t xbase = (size_t)b * 128 * 2048;
  for (int kt = 0; kt < 2; ++kt) {
    const int g0 = kt * 64;
#pragma unroll
    for (int j = 0; j < 16; ++j) {
      int idx = tid + j * 256;
      int f = idx >> 6, g = idx & 63;
      Wt[g * 68 + f] = ldin(W, Wbase + (size_t)f * 128 + g0 + g, isbf);
    }
#pragma unroll
    for (int j = 0; j < 16; ++j) {
      int idx = tid + j * 256;
      int g = idx >> 6, nn = idx & 63;
      Xs[g * 64 + nn] = ldin(x, xbase + (size_t)(g0 + g) * 2048 + n0 + nn, isbf);
    }
    __syncthreads();
#pragma unroll 4
    for (int g = 0; g < 64; ++g) {
      float4 wv = *(const float4*)&Wt[g * 68 + tf * 4];
      float4 xv = *(const float4*)&Xs[g * 64 + tn * 4];
      acc[0][0] += wv.x * xv.x; acc[0][1] += wv.x * xv.y; acc[0][2] += wv.x * xv.z; acc[0][3] += wv.x * xv.w;
      acc[1][0] += wv.y * xv.x; acc[1][1] += wv.y * xv.y; acc[1][2] += wv.y * xv.z; acc[1][3] += wv.y * xv.w;
      acc[2][0] += wv.z * xv.x; acc[2][1] += wv.z * xv.y; acc[2][2] += wv.z * xv.z; acc[2][3] += wv.z * xv.w;
      acc[3][0] += wv.w * xv.x; acc[3][1] += wv.w * xv.y; acc[3][2] += wv.w * xv.z; acc[3][3] += wv.w * xv.w;
    }
    __syncthreads();
  }
  // Wx store, node-major: Wx[(n*16 + bp)*64 + f]
#pragma unroll
  for (int j = 0; j < 4; ++j) {
    int n = n0 + tn * 4 + j;
    u32 lo = (u32)f2b(acc[0][j]) | ((u32)f2b(acc[1][j]) << 16);
    u32 hi = (u32)f2b(acc[2][j]) | ((u32)f2b(acc[3][j]) << 16);
    *(uint2*)(Wx + ((size_t)(n * 16 + bp) * 64 + tf * 4)) = make_uint2(lo, hi);
  }
  float a1v[4], a2v[4];
#pragma unroll
  for (int fi = 0; fi < 4; ++fi) {
    a1v[fi] = ldin(a, (size_t)p * 128 + tf * 4 + fi, isbf);
    a2v[fi] = ldin(a, (size_t)p * 128 + 64 + tf * 4 + fi, isbf);
  }
  float* red1 = Wt;             // 64*17 floats
  float* red2 = Wt + 64 * 17;   // 64*17 floats
#pragma unroll
  for (int j = 0; j < 4; ++j) {
    float p1 = a1v[0] * acc[0][j] + a1v[1] * acc[1][j] + a1v[2] * acc[2][j] + a1v[3] * acc[3][j];
    float p2 = a2v[0] * acc[0][j] + a2v[1] * acc[1][j] + a2v[2] * acc[2][j] + a2v[3] * acc[3][j];
    red1[(tn * 4 + j) * 17 + tf] = p1;
    red2[(tn * 4 + j) * 17 + tf] = p2;
  }
  __syncthreads();
  if (tid < 64) {
    float v1 = 0.f, v2 = 0.f;
#pragma unroll
    for (int k = 0; k < 16; ++k) {
      v1 += red1[tid * 17 + k];
      v2 += red2[tid * 17 + k];
    }
    s1t[(size_t)(n0 + tid) * 16 + bp] = v1;
    s2t[(size_t)(n0 + tid) * 16 + bp] = v2;
  }
}

// ---------------- K2: block per row. Row lists (packed n|slot|has_slot + sv) via prefix scan;
// column lists via line-padded atomics. ----------------
__global__ __launch_bounds__(256) void k_csc(const void* __restrict__ S,
                                             u32* __restrict__ cnt_p,
                                             u32* __restrict__ col_m,
                                             float* __restrict__ col_v,
                                             u32* __restrict__ rcnt,
                                             u32* __restrict__ row_e,
                                             float* __restrict__ row_v,
                                             const u32* __restrict__ flag) {
  __shared__ u32 wsum[4];
  const int isbf = (int)flag[0];
  const int m = blockIdx.x;
  const int tid = threadIdx.x;
  const int lane = tid & 63, wid = tid >> 6;
  const int n0 = tid * 8;
  float v[8];
  if (isbf) {
    uint4 pk = ((const uint4*)S)[(size_t)m * 256 + tid];
    u32 wv[4] = {pk.x, pk.y, pk.z, pk.w};
#pragma unroll
    for (int j = 0; j < 4; ++j) {
      v[2 * j]     = b2f((u16)(wv[j] & 0xffffu));
      v[2 * j + 1] = b2f((u16)(wv[j] >> 16));
    }
  } else {
    float4 f0 = ((const float4*)S)[(size_t)m * 512 + 2 * tid];
    float4 f1 = ((const float4*)S)[(size_t)m * 512 + 2 * tid + 1];
    v[0] = f0.x; v[1] = f0.y; v[2] = f0.z; v[3] = f0.w;
    v[4] = f1.x; v[5] = f1.y; v[6] = f1.z; v[7] = f1.w;
  }
  u32 rflags = 0, rc = 0;
#pragma unroll
  for (int j = 0; j < 8; ++j) {
    const int n = n0 + j;
    const float svd = (n == m) ? v[j] + 1.f : v[j];
    if (fabsf(svd) > ZTOLF) { rflags |= 1u << j; rc++; }
  }
  u32 inc = rc;
#pragma unroll
  for (int off = 1; off < 64; off <<= 1) {
    u32 y = __shfl_up(inc, off);
    if (lane >= off) inc += y;
  }
  if (lane == 63) wsum[wid] = inc;
  __syncthreads();
  u32 wbase = 0;
#pragma unroll
  for (int k = 0; k < 4; ++k) wbase += (k < wid) ? wsum[k] : 0u;
  u32 pos = wbase + inc - rc;
#pragma unroll
  for (int j = 0; j < 8; ++j) {
    const int n = n0 + j;
    const float sv = v[j];
    u32 slot = 0xffffffffu;
    if (sv != 0.f) {
      u32 s = atomicAdd(&cnt_p[(size_t)n * 16], 1u);
      if (s < CAP) {
        col_m[(size_t)n * CAP + s] = (u32)m;
        col_v[(size_t)n * CAP + s] = sv;
        slot = s;
      }
    }
    if ((rflags >> j) & 1u) {
      if (pos < CAP) {
        const u32 hs = (slot != 0xffffffffu) ? 1u : 0u;
        row_e[(size_t)m * CAP + pos] = (u32)n | ((slot & 0xffu) << 11) | (hs << 19);
        row_v[(size_t)m * CAP + pos] = sv;
      }
      pos++;
    }
  }
  if (tid == 255) rcnt[m] = min(wbase + inc, (u32)CAP);
}

// ---------------- K3: sparse softmax stats (wave per row) + bf16 weight scatter to col_wb ----------------
__global__ __launch_bounds__(256) void k_rows(const u32* __restrict__ rcnt,
                                              const u32* __restrict__ row_e,
                                              const float* __restrict__ row_v,
                                              const float* __restrict__ s1t,
                                              const float* __restrict__ s2t,
                                              u16* __restrict__ col_wb) {
  __shared__ float4 stat_s[4][16];   // per-wave (s2, rowmax, invsum, 0)
  const int tid = threadIdx.x;
  const int lane = tid & 63, wv = tid >> 6;
  const int m = blockIdx.x * 4 + wv;      // one wave per row
  const int c2 = min((int)rcnt[m], CAP);
  u32 pk[4];
#pragma unroll
  for (int I = 0; I < 4; ++I) {
    int i = lane + I * 64;
    pk[I] = (i < c2) ? row_e[(size_t)m * CAP + i] : 0xffffffffu;
  }
  const float s2v = (lane < 16) ? s2t[(size_t)m * 16 + lane] : 0.f;
  float my_rmx = 0.f, my_inv = 0.f;
#pragma unroll
  for (int g = 0; g < 4; ++g) {           // bp groups of 4
    float4 sg[4];
#pragma unroll
    for (int I = 0; I < 4; ++I)
      sg[I] = (pk[I] != 0xffffffffu)
                ? *(const float4*)&s1t[(size_t)(pk[I] & 0x7ffu) * 16 + g * 4]
                : make_float4(-3e38f, -3e38f, -3e38f, -3e38f);
#pragma unroll
    for (int q = 0; q < 4; ++q) {
      const int bp = g * 4 + q;
      const float s2m = __shfl(s2v, bp);
      float s1max = -3e38f;
#pragma unroll
      for (int I = 0; I < 4; ++I) {
        float xv = (q == 0) ? sg[I].x : (q == 1) ? sg[I].y : (q == 2) ? sg[I].z : sg[I].w;
        s1max = fmaxf(s1max, xv);
      }
#pragma unroll
      for (int off = 32; off; off >>= 1) s1max = fmaxf(s1max, __shfl_xor(s1max, off));
      float rmx = s2m + s1max;
      rmx = rmx >= 0.f ? rmx : NEG_SLOPE * rmx;
      float sm = 0.f;
#pragma unroll
      for (int I = 0; I < 4; ++I) {
        float xv = (q == 0) ? sg[I].x : (q == 1) ? sg[I].y : (q == 2) ? sg[I].z : sg[I].w;
        float e = xv + s2m;
        e = e >= 0.f ? e : NEG_SLOPE * e;
        sm += __expf(e - rmx);
      }
#pragma unroll
      for (int off = 32; off; off >>= 1) sm += __shfl_xor(sm, off);
      const bool any = (s1max > -1e38f);
      const float rmxo = any ? rmx : 0.f;
      const float inv = any ? 1.f / sm : 0.f;
      if (lane == bp) { my_rmx = rmxo; my_inv = inv; }
    }
  }
  if (lane < 16) stat_s[wv][lane] = make_float4(s2v, my_rmx, my_inv, 0.f);
  // phase 2: bf16 weight scatter (32 B per entry)
#pragma unroll
  for (int I = 0; I < 4; ++I) {
    const u32 p = pk[I];
    if (p == 0xffffffffu) continue;
    if (!((p >> 19) & 1u)) continue;      // no column slot (pure-diagonal sv==0)
    const int n = (int)(p & 0x7ffu);
    const int slot = (int)((p >> 11) & 0xffu);
    const float sv = row_v[(size_t)m * CAP + lane + I * 64];
    u32 packed[8];
#pragma unroll
    for (int g = 0; g < 4; ++g) {
      const float4 s1v = *(const float4*)&s1t[(size_t)n * 16 + g * 4];
      float wq[4];
#pragma unroll
      for (int q = 0; q < 4; ++q) {
        const float4 st = stat_s[wv][g * 4 + q];
        float xv = (q == 0) ? s1v.x : (q == 1) ? s1v.y : (q == 2) ? s1v.z : s1v.w;
        float e = xv + st.x;
        e = e >= 0.f ? e : NEG_SLOPE * e;
        wq[q] = sv * __expf(e - st.y) * st.z;
      }
      packed[g * 2]     = (u32)f2b(wq[0]) | ((u32)f2b(wq[1]) << 16);
      packed[g * 2 + 1] = (u32)f2b(wq[2]) | ((u32)f2b(wq[3]) << 16);
    }
    uint4* dst = (uint4*)(col_wb + ((size_t)n * CAP + slot) * 16);
    dst[0] = make_uint4(packed[0], packed[1], packed[2], packed[3]);
    dst[1] = make_uint4(packed[4], packed[5], packed[6], packed[7]);
  }
}

// ---------------- K4: y[bp][f][n] = relu( sum_m Wx[m][bp][f] * w[m][n][bp] ) ----------------
// 512 threads: 8 waves = 4 bp-groups x 2 entry-halves. Node-major Wx: one wave-load = 512 B contiguous.
__global__ __launch_bounds__(512, 8) void k_out(const u16* __restrict__ Wx,
                                                const u32* __restrict__ cnt_p,
                                                const u32* __restrict__ col_m,
                                                const float* __restrict__ col_v,
                                                const u16* __restrict__ col_wb,
                                                void* __restrict__ out,
                                                const u32* __restrict__ flag) {
  __shared__ u32 lds_mo[CAP];        // m*1024 element offsets (u16 units)
  __shared__ float lds_w[CAP * 16];  // [i][bp] f32, 16 KB
  __shared__ float lds_r[256 * 4];   // half-1 partials (4 KB)
  const int isbf = (int)flag[0];
  const int tid = threadIdx.x;
  const int bid = blockIdx.x;
  const int n = ((bid & 7) << 8) | (bid >> 3);   // XCD swizzle
  const int c = min((int)cnt_p[(size_t)n * 16], CAP);
  const int cpad = (c + 15) & ~15;               // 2 halves x unroll-8
  u32 mreg = 0; float svreg = 0.f;
  if (tid < cpad) {
    mreg  = (tid < c) ? col_m[(size_t)n * CAP + tid] : 0u;
    svreg = (tid < c) ? col_v[(size_t)n * CAP + tid] : 0.f;
  }
  // stage weights: bf16 -> f32 LDS. k = (entry, quad of 4 bp); uint2 = 4 bf16.
  const uint2* cw2 = (const uint2*)(col_wb + (size_t)n * CAP * 16);
  const int w4 = cpad * 4;
  for (int k = tid; k < w4; k += 512) {
    float4 wv = make_float4(0.f, 0.f, 0.f, 0.f);
    if (k < c * 4) {
      uint2 pk = cw2[k];
      wv.x = b2f((u16)(pk.x & 0xffffu));
      wv.y = b2f((u16)(pk.x >> 16));
      wv.z = b2f((u16)(pk.y & 0xffffu));
      wv.w = b2f((u16)(pk.y >> 16));
    }
    ((float4*)lds_w)[k] = wv;
  }
  __syncthreads();
  if (tid < cpad) {
    if (tid < c && (int)mreg == n && fabsf(svreg + 1.f) <= ZTOLF) {
      // masked-out diagonal (|S+I| <= tol): weight is exactly 0, never written by k_rows
#pragma unroll
      for (int q = 0; q < 4; ++q) ((float4*)lds_w)[tid * 4 + q] = make_float4(0.f, 0.f, 0.f, 0.f);
    }
    lds_mo[tid] = mreg * 1024u;      // u16 element offset of node m's slab
  }
  __syncthreads();
  const int lane = tid & 63, wvi = tid >> 6;
  const int h = wvi >> 2;
  const int bp = (wvi & 3) * 4 + (lane >> 4);
  const int f4 = lane & 15;
  const u16* wxp = Wx + (size_t)bp * 64 + f4 * 4;   // + m*1024 per entry (contiguous 512 B per wave)
  float ac0 = 0.f, ac1 = 0.f, ac2 = 0.f, ac3 = 0.f;
  for (int base = h * 8; base < cpad; base += 16) {
    uint2 wd[8]; float ww[8];
#pragma unroll
    for (int j = 0; j < 8; ++j) {
      const int i = base + j;
      const u32 off = lds_mo[i];
      wd[j] = *(const uint2*)(wxp + off);
      ww[j] = lds_w[i * 16 + bp];
    }
#pragma unroll
    for (int j = 0; j < 8; ++j) {
      const float w = ww[j];
      ac0 += w * b2f((u16)(wd[j].x & 0xffffu));
      ac1 += w * b2f((u16)(wd[j].x >> 16));
      ac2 += w * b2f((u16)(wd[j].y & 0xffffu));
      ac3 += w * b2f((u16)(wd[j].y >> 16));
    }
  }
  if (h == 1)
    *(float4*)&lds_r[(bp * 16 + f4) * 4] = make_float4(ac0, ac1, ac2, ac3);
  __syncthreads();
  if (h == 0) {
    float4 r = *(const float4*)&lds_r[(bp * 16 + f4) * 4];
    const float o0 = fmaxf(ac0 + r.x, 0.f), o1 = fmaxf(ac1 + r.y, 0.f);
    const float o2 = fmaxf(ac2 + r.z, 0.f), o3 = fmaxf(ac3 + r.w, 0.f);
    const size_t r0 = (size_t)(bp * 64 + f4 * 4);
    if (isbf) {
      u16* ob = (u16*)out;
      ob[(r0 + 0) * 2048 + n] = f2b(o0);
      ob[(r0 + 1) * 2048 + n] = f2b(o1);
      ob[(r0 + 2) * 2048 + n] = f2b(o2);
      ob[(r0 + 3) * 2048 + n] = f2b(o3);
    } else {
      float* of = (float*)out;
      of[(r0 + 0) * 2048 + n] = o0;
      of[(r0 + 1) * 2048 + n] = o1;
      of[(r0 + 2) * 2048 + n] = o2;
      of[(r0 + 3) * 2048 + n] = o3;
    }
  }
}

extern "C" void kernel_launch(void* const* d_in, const int* in_sizes, int n_in,
                              void* d_out, int out_size, void* d_ws, size_t ws_size,
                              hipStream_t stream) {
  // inputs (dtype auto-detected): x (4,128,2048), a (4,1,128), W (4,1,64,128), S (1,2048,2048)
  const void* x = d_in[0];
  const void* a = d_in[1];
  const void* W = d_in[2];
  const void* S = d_in[3];

  char* ws = (char*)d_ws;
  u16* Wx      = (u16*)ws;                               // 4 MiB   [m][bp][f] node-major
  float* s1t   = (float*)(ws + 4u * 1024 * 1024);        // 128 KiB
  float* s2t   = s1t + 2048 * 16;                        // 128 KiB
  u32* cnt_p   = (u32*)(s2t + 2048 * 16);                // 128 KiB (1 counter / 64B line)
  u32* rcnt    = cnt_p + 2048 * 16;                      // 8 KiB
  u32* col_m   = rcnt + 2048;                            // 2 MiB
  float* col_v = (float*)(col_m + 2048 * CAP);           // 2 MiB
  u32* row_e   = (u32*)(col_v + 2048 * CAP);             // 2 MiB
  float* row_v = (float*)(row_e + 2048 * CAP);           // 2 MiB
  u16* col_wb  = (u16*)(row_v + 2048 * CAP);             // 2048*CAP*16*2 = 16 MiB (bf16 weights)
  u32* flag    = (u32*)(col_wb + (size_t)2048 * CAP * 16); // 4 B
  // total ~28.5 MiB

  k_detect<<<1, 256, 0, stream>>>((const u32*)x, flag, (uint4*)cnt_p, (uint4*)rcnt);
  k_wx<<<dim3(32, 16), 256, 0, stream>>>(x, W, a, Wx, s1t, s2t, flag);
  k_csc<<<2048, 256, 0, stream>>>(S, cnt_p, col_m, col_v, rcnt, row_e, row_v, flag);
  k_rows<<<512, 256, 0, stream>>>(rcnt, row_e, row_v, s1t, s2t, col_wb);
  k_out<<<2048, 512, 0, stream>>>(Wx, cnt_p, col_m, col_v, col_wb, d_out, flag);
}